// Round 1
// 470.743 us; speedup vs baseline: 1.0471x; 1.0471x over previous
//
#include <hip/hip_runtime.h>
#include <cstdint>
#include <cstddef>

// ---------- types & helpers ----------
typedef __bf16 bf16x8 __attribute__((ext_vector_type(8)));
typedef float  f32x4  __attribute__((ext_vector_type(4)));
typedef unsigned short u16x4 __attribute__((ext_vector_type(4)));

typedef __attribute__((address_space(1))) void* gas1_t;
typedef __attribute__((address_space(3))) void* las3_t;

__device__ __forceinline__ unsigned short f2bf(float f) {
  union { float f; unsigned u; } v; v.f = f;
  unsigned r = v.u + 0x7fffu + ((v.u >> 16) & 1u);   // RNE
  return (unsigned short)(r >> 16);
}
__device__ __forceinline__ float bf2f(unsigned short h) {
  union { unsigned u; float f; } v; v.u = ((unsigned)h) << 16;
  return v.f;
}

// ---------- problem constants ----------
constexpr int Bc = 4, Lc = 8192, Dc = 1024, NSAMP = 2048;
constexpr int ROWS = Bc * Lc;        // 32768
constexpr int NSEL = Bc * NSAMP;     // 8192
constexpr long long Y_ELEMS = (long long)ROWS * Dc;          // 33554432
constexpr long long GRAD_OFF = Y_ELEMS;                      // grad after y
constexpr long long LOSS_OFF = GRAD_OFF + (long long)Dc*Dc;  // 34603008

// ---------- generic B^T GEMM: C[m][n] = sum_k A[m][k]*B[n][k], bf16 in, fp32 acc ----------
// MODE 0: nt-store Cf = acc + bias[col]   (y; output never re-read -> bypass caches)
// MODE 2: Cf = acc                        (xs; re-read by stats -> cached stores)
// MODE 3: atomicAdd(Cf, acc)              (split-K accumulate: M and G)
constexpr int BM = 128, BN = 128, BK = 64;

template<int MODE>
__global__ void gemm_bt(const unsigned short* __restrict__ A,
                        const unsigned short* __restrict__ B,
                        float* __restrict__ Cf,
                        const float* __restrict__ bias,
                        int M, int N, int K, int kchunk) {
  __shared__ unsigned short sA[BM * BK];   // 16 KB
  __shared__ unsigned short sB[BN * BK];   // 16 KB
  const int tid  = threadIdx.x;
  const int lane = tid & 63;
  const int wave = tid >> 6;
  const int wm = wave >> 1, wn = wave & 1;     // 2x2 waves, each 64x64
  const int q = lane >> 4, r16 = lane & 15;

  // T1: XCD-aware bijective block swizzle.
  // HW assigns XCD = flat_block_id % 8. All our grids have gridDim.x == 8 and
  // per-z-slice nwg % 8 == 0 (2048 / 512 / 64 / 64), and z*nwg = 0 (mod 8), so
  // swz = (orig%8)*(nwg/8) + orig/8 gives each XCD a CONTIGUOUS chunk of tiles:
  // consecutive M-panels x all N-tiles -> A-panel read by exactly one XCD,
  // B fully L2-resident per XCD.
  const int gx   = gridDim.x;
  const int nwg  = gx * gridDim.y;
  const int orig = blockIdx.y * gx + blockIdx.x;
  const int swz  = (orig & 7) * (nwg >> 3) + (orig >> 3);
  const int m0 = (swz / gx) * BM;
  const int n0 = (swz % gx) * BN;
  const int kb = blockIdx.z * kchunk;

  const int lrow = lane >> 3;        // 0..7 rows within 1KB chunk
  const int lcol = (lane & 7) * 8;   // bf16 elems; 8 elems = 16B

  f32x4 acc[4][4] = {};

  for (int k0 = kb; k0 < kb + kchunk; k0 += BK) {
#pragma unroll
    for (int j = 0; j < 4; ++j) {
      const int c = wave * 4 + j;
      const int row = c * 8 + lrow;
      const unsigned short* ga = A + (size_t)(m0 + row) * K + k0 + lcol;
      __builtin_amdgcn_global_load_lds((gas1_t)(void*)ga, (las3_t)(sA + c * 512), 16, 0, 0);
      const unsigned short* gb = B + (size_t)(n0 + row) * K + k0 + lcol;
      __builtin_amdgcn_global_load_lds((gas1_t)(void*)gb, (las3_t)(sB + c * 512), 16, 0, 0);
    }
    __syncthreads();
#pragma unroll
    for (int kk = 0; kk < BK; kk += 32) {
      bf16x8 af[4], bfv[4];
#pragma unroll
      for (int mi = 0; mi < 4; ++mi)
        af[mi] = *(const bf16x8*)(sA + (size_t)(wm*64 + mi*16 + r16) * BK + kk + q*8);
#pragma unroll
      for (int ni = 0; ni < 4; ++ni)
        bfv[ni] = *(const bf16x8*)(sB + (size_t)(wn*64 + ni*16 + r16) * BK + kk + q*8);
#pragma unroll
      for (int mi = 0; mi < 4; ++mi)
#pragma unroll
        for (int ni = 0; ni < 4; ++ni)
          acc[mi][ni] = __builtin_amdgcn_mfma_f32_16x16x32_bf16(af[mi], bfv[ni], acc[mi][ni], 0, 0, 0);
    }
    __syncthreads();
  }

  // epilogue: lane holds C[row = q*4+r][col = r16] per 16x16 tile (m89/m91 layout)
  // Store order: ni INNERMOST so the 2 instructions covering one 128B line
  // (cols 0-15 / 16-31 of a row) issue back-to-back -> full-line write combine.
  const int row0 = m0 + wm*64 + q*4;
  const int col0 = n0 + wn*64 + r16;
  float bv[4] = {0.f, 0.f, 0.f, 0.f};
  if (MODE == 0) {
#pragma unroll
    for (int ni = 0; ni < 4; ++ni) bv[ni] = bias[col0 + ni*16];
  }
#pragma unroll
  for (int mi = 0; mi < 4; ++mi) {
#pragma unroll
    for (int r = 0; r < 4; ++r) {
      const int row = row0 + mi*16 + r;
      const size_t base = (size_t)row * N + col0;
#pragma unroll
      for (int ni = 0; ni < 4; ++ni) {
        const size_t o = base + (size_t)ni * 16;
        float v = acc[mi][ni][r];
        if (MODE == 0)      __builtin_nontemporal_store(v + bv[ni], &Cf[o]);
        else if (MODE == 2) Cf[o] = v;
        else                atomicAdd(&Cf[o], v);
      }
    }
  }
}

// ---------- fp32 -> bf16 bulk convert (4 elems/thread); NT==1 streams the fp32 read ----------
template<int NT>
__global__ void cvt_f32_bf16(const float* __restrict__ in, unsigned short* __restrict__ out, long long n) {
  long long i = ((long long)blockIdx.x * 256 + threadIdx.x) * 4;
  if (i >= n) return;
  f32x4 v;
  if (NT) v = __builtin_nontemporal_load((const f32x4*)(in + i));
  else    v = *(const f32x4*)(in + i);
  u16x4 o;
  o.x = f2bf(v.x); o.y = f2bf(v.y); o.z = f2bf(v.z); o.w = f2bf(v.w);
  *(u16x4*)(out + i) = o;
}

// ---------- gather sampled tokens from bf16 x: ab[blk][:] = xb[b][idx][:] ----------
__global__ void gather_rows(const unsigned short* __restrict__ xb, const int* __restrict__ idx,
                            unsigned short* __restrict__ out) {
  const int blk = blockIdx.x;            // 0..8191 = b*2048+n
  const int b = blk >> 11, n = blk & 2047;
  const int row = idx[b * NSAMP + n];
  const unsigned short* src = xb + ((size_t)b * Lc + row) * Dc;
  unsigned short* dst = out + (size_t)blk * Dc;
  const int c = threadIdx.x * 4;
  *(u16x4*)(dst + c) = *(const u16x4*)(src + c);
}

// ---------- diagonal residual: c[i] = d_ii - bf16(d_ii) ----------
__global__ void diag_resid(const float* __restrict__ dc, float* __restrict__ cvec) {
  const int i = blockIdx.x * 256 + threadIdx.x;
  if (i >= Dc) return;
  const float v = dc[(size_t)i * Dc + i];
  cvec[i] = v - bf2f(f2bf(v));
}

// ---------- fp32 transpose -> bf16 (64x64 LDS tiles): outT[c][r] = bf16(in[r][c]) ----------
__global__ void transpose_bf16(const float* __restrict__ in, unsigned short* __restrict__ outT,
                               int R, int C) {
  __shared__ float tile[64][65];
  const int r0 = blockIdx.y * 64, c0 = blockIdx.x * 64;
  const int t = threadIdx.x;
  const int c = t & 63, r4 = t >> 6;
#pragma unroll
  for (int j = 0; j < 16; ++j) {
    const int r = j * 4 + r4;
    tile[r][c] = in[(size_t)(r0 + r) * C + c0 + c];
  }
  __syncthreads();
  const int i = t >> 2, p = t & 3;
  unsigned short* dst = outT + (size_t)(c0 + i) * R + r0 + p * 16;
#pragma unroll
  for (int j = 0; j < 16; j += 4) {
    u16x4 v;
    v.x = f2bf(tile[p*16 + j + 0][i]);
    v.y = f2bf(tile[p*16 + j + 1][i]);
    v.z = f2bf(tile[p*16 + j + 2][i]);
    v.w = f2bf(tile[p*16 + j + 3][i]);
    *(u16x4*)(dst + j) = v;
  }
}

// ---------- fused xs pass: diag correction; per-row s1=Σx²,s2=Σx⁴; per-col Σx²; bf16 transpose ----------
__global__ void xs_stats_transpose(const float* __restrict__ xs, const unsigned short* __restrict__ ab,
                                   const float* __restrict__ cvec,
                                   unsigned short* __restrict__ xsT,
                                   float* __restrict__ m2sum, float* __restrict__ s1g,
                                   float* __restrict__ s2g) {
  __shared__ float tile[64][65];
  const int n0 = blockIdx.x * 64;   // sample rows (8192)
  const int i0 = blockIdx.y * 64;   // feature cols (1024)
  const int t = threadIdx.x;
  const int c = t & 63, r4 = t >> 6;
  const float ccol = cvec[i0 + c];
#pragma unroll
  for (int j = 0; j < 16; ++j) {
    const int r = j * 4 + r4;
    const size_t o = (size_t)(n0 + r) * Dc + i0 + c;
    tile[r][c] = xs[o] + bf2f(ab[o]) * ccol;   // exact-diag correction
  }
  __syncthreads();
  if (t < 64) {
    float s1 = 0.f, s2 = 0.f;
#pragma unroll
    for (int cc = 0; cc < 64; ++cc) { float v = tile[t][cc]; float v2 = v*v; s1 += v2; s2 += v2*v2; }
    atomicAdd(&s1g[n0 + t], s1);
    atomicAdd(&s2g[n0 + t], s2);
  } else if (t < 128) {
    const int col = t - 64;
    float cs = 0.f;
#pragma unroll
    for (int rr = 0; rr < 64; ++rr) { float v = tile[rr][col]; cs += v*v; }
    atomicAdd(&m2sum[i0 + col], cs);
  }
  const int i = t >> 2, p = t & 3;
  unsigned short* dst = xsT + (size_t)(i0 + i) * NSEL + n0 + p * 16;
#pragma unroll
  for (int j = 0; j < 16; j += 4) {
    u16x4 v;
    v.x = f2bf(tile[p*16 + j + 0][i]);
    v.y = f2bf(tile[p*16 + j + 1][i]);
    v.z = f2bf(tile[p*16 + j + 2][i]);
    v.w = f2bf(tile[p*16 + j + 3][i]);
    *(u16x4*)(dst + j) = v;
  }
}

// ---------- grad writeout: off-diag 0.5*G/N, diag 0.5*(m2-1) ----------
__global__ void grad_write(const float* __restrict__ G, const float* __restrict__ m2sum,
                           float* __restrict__ out) {
  const int i = blockIdx.x * 256 + threadIdx.x;   // 0..1048575
  const int r = i >> 10, c = i & 1023;
  float g = G[i] * (0.5f / (float)NSEL);
  if (r == c) g = 0.5f * (m2sum[r] * (1.0f / (float)NSEL) - 1.0f);
  __builtin_nontemporal_store(g, &out[i]);
}

// ---------- losses: corr=(Σs1²−Σs2)/denom, white=(Σs2−2Σs1+N·d)/denom ----------
__global__ void finalize_losses(const float* __restrict__ s1g, const float* __restrict__ s2g,
                                float* __restrict__ out2) {
  __shared__ double sa[256], sb[256], sc[256];
  double a = 0, b = 0, c = 0;
  for (int n = threadIdx.x; n < NSEL; n += 256) {
    double s1 = s1g[n], s2 = s2g[n];
    a += s1 * s1; b += s2; c += s1;
  }
  const int t = threadIdx.x;
  sa[t] = a; sb[t] = b; sc[t] = c;
  __syncthreads();
  for (int s = 128; s > 0; s >>= 1) {
    if (t < s) { sa[t] += sa[t+s]; sb[t] += sb[t+s]; sc[t] += sc[t+s]; }
    __syncthreads();
  }
  if (t == 0) {
    const double denom = (double)NSEL * (double)Dc * (double)Dc;
    const double cnt   = (double)NSEL * (double)Dc;
    out2[0] = (float)((sa[0] - sb[0]) / denom);
    out2[1] = (float)((sb[0] - 2.0 * sc[0] + cnt) / denom);
  }
}

extern "C" void kernel_launch(void* const* d_in, const int* in_sizes, int n_in,
                              void* d_out, int out_size, void* d_ws, size_t ws_size,
                              hipStream_t stream) {
  const float* x      = (const float*)d_in[0];
  const float* W      = (const float*)d_in[1];
  const float* bias   = (const float*)d_in[2];
  const float* decorr = (const float*)d_in[3];
  const int*   sidx   = (const int*)d_in[4];
  float* out = (float*)d_out;

  // workspace layout (bytes)
  char* w = (char*)d_ws;
  constexpr size_t SZ_XB  = (size_t)ROWS * Dc * 2;       // x bf16            64 MB
  constexpr size_t SZ_AB  = (size_t)NSEL * Dc * 2;       // gathered sel bf16 16 MB
  constexpr size_t SZ_DT  = (size_t)Dc * Dc * 2;         // decorr^T bf16      2 MB
  constexpr size_t SZ_WB  = (size_t)Dc * Dc * 2;         // W bf16             2 MB
  constexpr size_t SZ_MB  = (size_t)Dc * Dc * 2;         // M bf16             2 MB
  constexpr size_t SZ_XS  = (size_t)NSEL * Dc * 4;       // xs fp32           32 MB
  constexpr size_t SZ_XST = (size_t)Dc * NSEL * 2;       // xs^T bf16         16 MB
  constexpr size_t SZ_MF  = (size_t)Dc * Dc * 4;         // M fp32 acc         4 MB (zeroed)
  constexpr size_t SZ_GB  = (size_t)Dc * Dc * 4;         // G fp32 acc         4 MB (zeroed)
  constexpr size_t SZ_M2  = (size_t)Dc * 4;
  constexpr size_t SZ_S1  = (size_t)NSEL * 4;
  constexpr size_t SZ_S2  = (size_t)NSEL * 4;
  constexpr size_t SZ_CV  = (size_t)Dc * 4;

  size_t off = 0;
  unsigned short* xb  = (unsigned short*)(w + off); off += SZ_XB;
  unsigned short* ab  = (unsigned short*)(w + off); off += SZ_AB;
  unsigned short* dT  = (unsigned short*)(w + off); off += SZ_DT;
  unsigned short* wb  = (unsigned short*)(w + off); off += SZ_WB;
  unsigned short* mb  = (unsigned short*)(w + off); off += SZ_MB;
  float*          xsf = (float*)(w + off);          off += SZ_XS;
  unsigned short* xsT = (unsigned short*)(w + off); off += SZ_XST;
  float*          cv  = (float*)(w + off);          off += SZ_CV;
  char*           zbase = w + off;                   // zeroed region
  float*          Mf  = (float*)(w + off);          off += SZ_MF;
  float*          Gb  = (float*)(w + off);          off += SZ_GB;
  float*          m2s = (float*)(w + off);          off += SZ_M2;
  float*          s1g = (float*)(w + off);          off += SZ_S1;
  float*          s2g = (float*)(w + off);          off += SZ_S2;
  const size_t zbytes = SZ_MF + SZ_GB + SZ_M2 + SZ_S1 + SZ_S2;

  (void)hipMemsetAsync(zbase, 0, zbytes, stream);

  // prep
  cvt_f32_bf16<1><<<(int)(Y_ELEMS / 1024), 256, 0, stream>>>(x, xb, Y_ELEMS);
  cvt_f32_bf16<0><<<Dc*Dc / 1024, 256, 0, stream>>>(W, wb, (long long)Dc*Dc);
  diag_resid<<<4, 256, 0, stream>>>(decorr, cv);
  transpose_bf16<<<dim3(Dc/64, Dc/64), 256, 0, stream>>>(decorr, dT, Dc, Dc);
  gather_rows<<<NSEL, 256, 0, stream>>>(xb, sidx, ab);

  // M = W @ decorr : split-K=8 atomic fp32 (512 blocks), then cvt to bf16
  gemm_bt<3><<<dim3(Dc/BN, Dc/BM, 8), 256, 0, stream>>>(wb, dT, Mf, nullptr, Dc, Dc, Dc, Dc/8);
  cvt_f32_bf16<0><<<Dc*Dc / 1024, 256, 0, stream>>>(Mf, mb, (long long)Dc*Dc);

  // y = x @ M^T + bias (nt stores)
  gemm_bt<0><<<dim3(Dc/BN, ROWS/BM, 1), 256, 0, stream>>>(xb, mb, out, bias, ROWS, Dc, Dc, Dc);

  // xs = sel @ decorr^T (bf16, K=1024; diag corrected downstream)
  gemm_bt<2><<<dim3(Dc/BN, NSEL/BM, 1), 256, 0, stream>>>(ab, dT, xsf, nullptr, NSEL, Dc, Dc, Dc);

  // stats + correction + transpose
  xs_stats_transpose<<<dim3(NSEL/64, Dc/64), 256, 0, stream>>>(xsf, ab, cv, xsT, m2s, s1g, s2g);

  // G = xs^T xs : split-K=16 atomic (1024 blocks)
  gemm_bt<3><<<dim3(Dc/BN, Dc/BM, 16), 256, 0, stream>>>(xsT, xsT, Gb, nullptr, Dc, Dc, NSEL, NSEL/16);

  // outputs
  grad_write<<<Dc*Dc / 256, 256, 0, stream>>>(Gb, m2s, out + GRAD_OFF);
  finalize_losses<<<1, 256, 0, stream>>>(s1g, s2g, out + LOSS_OFF);
}